// Round 1
// baseline (202.962 us; speedup 1.0000x reference)
//
#include <hip/hip_runtime.h>
#include <hip/hip_bf16.h>

#define N_NODES 100000
#define IN_DIM  128
#define HIDDEN  64
#define N_EDGES 1600000

typedef unsigned short u16;
typedef unsigned int   u32;

typedef __attribute__((ext_vector_type(8))) short bf16x8;  // 8 bf16 in 4 VGPRs
typedef __attribute__((ext_vector_type(4))) float f32x4;

__device__ __forceinline__ u16 f2bf(float f) {
    // round-to-nearest-even fp32 -> bf16
    u32 u = __float_as_uint(f);
    u32 r = 0x7FFFu + ((u >> 16) & 1u);
    u += r;
    return (u16)(u >> 16);
}

// ---------------------------------------------------------------------------
// Kernel 1: build WcatT[jj][k] (bf16, [128][128]) from W1 (fp32, [256][64]).
// Wcat[k][jj] = (jj < 64) ? W1[k][jj] : W1[128+k][jj-64]; stored transposed so
// MFMA B-fragment reads (n on lane&15, k contiguous) are 16B-contiguous.
// ---------------------------------------------------------------------------
__global__ __launch_bounds__(256) void prep_kernel(const float* __restrict__ W1,
                                                   u16* __restrict__ WcatT) {
    int idx = blockIdx.x * 256 + threadIdx.x;   // 0..16383
    int jj = idx >> 7;
    int k  = idx & 127;
    float v = (jj < 64) ? W1[k * 64 + jj] : W1[(128 + k) * 64 + (jj - 64)];
    WcatT[idx] = f2bf(v);
}

// ---------------------------------------------------------------------------
// Kernel 2: UV[m][jj] = sum_k z[m][k] * Wcat[k][jj]  (+ b1[jj] for jj<64)
// M-tile 64 per block (4 waves x 16 rows), N=128, K=128 single LDS tile.
// mfma_f32_16x16x32_bf16; A: m=lane&15, k=quad*8+j; B: n=lane&15, k=quad*8+j;
// D: col=lane&15, row=quad*4+reg (m89/m91-verified mappings).
// ---------------------------------------------------------------------------
#define MT  64
#define LDK 136   // 128 + 8 bf16 pad -> row stride 272 B (16B-aligned, breaks conflicts)

__global__ __launch_bounds__(256) void gemm_kernel(const float* __restrict__ z,
                                                   const u16* __restrict__ WcatT,
                                                   const float* __restrict__ b1,
                                                   u16* __restrict__ UV) {
    __shared__ u16 As[MT * LDK];    // 64 x 136 bf16  (17.4 KB)
    __shared__ u16 Bs[128 * LDK];   // 128 x 136 bf16 (34.8 KB)

    int tid = threadIdx.x;
    int m0  = blockIdx.x * MT;

    // Stage B (already bf16 in ws): 128 rows x 16 chunks of 16 B
    for (int c = tid; c < 128 * 16; c += 256) {
        int row = c >> 4, cc = c & 15;
        uint4 v = *(const uint4*)(WcatT + row * 128 + cc * 8);
        *(uint4*)(Bs + row * LDK + cc * 8) = v;
    }
    // Stage A with fp32->bf16 convert: 64 rows x 32 chunks of 4 floats
    for (int c = tid; c < MT * 32; c += 256) {
        int row = c >> 5, cc = c & 31;
        int gm = m0 + row;
        if (gm >= N_NODES) gm = N_NODES - 1;   // clamp; stores are guarded below
        float4 f = *(const float4*)(z + (size_t)gm * 128 + cc * 4);
        u32 lo = (u32)f2bf(f.x) | ((u32)f2bf(f.y) << 16);
        u32 hi = (u32)f2bf(f.z) | ((u32)f2bf(f.w) << 16);
        uint2 val; val.x = lo; val.y = hi;
        *(uint2*)(As + row * LDK + cc * 4) = val;
    }
    __syncthreads();

    int wave = tid >> 6;
    int lane = tid & 63;
    int quad = lane >> 4;
    int l16  = lane & 15;

    f32x4 acc[8];
    const f32x4 z4 = {0.f, 0.f, 0.f, 0.f};
#pragma unroll
    for (int i = 0; i < 8; i++) acc[i] = z4;

    int arow = wave * 16 + l16;   // local m for the A fragment
#pragma unroll
    for (int kb = 0; kb < 4; kb++) {
        int k0 = kb * 32 + quad * 8;
        bf16x8 a = *(const bf16x8*)(As + arow * LDK + k0);
#pragma unroll
        for (int nt = 0; nt < 8; nt++) {
            bf16x8 b = *(const bf16x8*)(Bs + (nt * 16 + l16) * LDK + k0);
            acc[nt] = __builtin_amdgcn_mfma_f32_16x16x32_bf16(a, b, acc[nt], 0, 0, 0);
        }
    }

    // Epilogue: add b1 to cols 0..63 (the U half), store bf16
#pragma unroll
    for (int nt = 0; nt < 8; nt++) {
        int col = nt * 16 + l16;
        float bias = (col < HIDDEN) ? b1[col] : 0.f;
#pragma unroll
        for (int r = 0; r < 4; r++) {
            int row = m0 + wave * 16 + quad * 4 + r;
            if (row < N_NODES) {
                UV[(size_t)row * 128 + col] = f2bf(acc[nt][r] + bias);
            }
        }
    }
}

// ---------------------------------------------------------------------------
// Kernel 3: per edge e: out[e] = sigmoid( sum_j relu(U[s][j]+V[d][j])*W2[j] + b2 )
// One thread per edge; 16 x 16B gathers from the 25.6 MB UV table (L3-resident).
// W2 is wave-uniform -> scalar loads.
// ---------------------------------------------------------------------------
__global__ __launch_bounds__(256) void edge_kernel(const int* __restrict__ ei,
                                                   const u16* __restrict__ UV,
                                                   const float* __restrict__ W2,
                                                   const float* __restrict__ b2,
                                                   float* __restrict__ out) {
    int e = blockIdx.x * 256 + threadIdx.x;
    if (e >= N_EDGES) return;
    int s = ei[e];
    int d = ei[N_EDGES + e];
    const uint4* up = (const uint4*)(UV + (size_t)s * 128);        // U' = z@W1a + b1
    const uint4* vp = (const uint4*)(UV + (size_t)d * 128 + 64);   // V  = z@W1b
    float acc = 0.f;
#pragma unroll
    for (int t = 0; t < 8; t++) {
        uint4 a = up[t];
        uint4 b = vp[t];
        u32 aw[4] = {a.x, a.y, a.z, a.w};
        u32 bw[4] = {b.x, b.y, b.z, b.w};
#pragma unroll
        for (int i = 0; i < 4; i++) {
            float u0 = __uint_as_float(aw[i] << 16);
            float u1 = __uint_as_float(aw[i] & 0xFFFF0000u);
            float v0 = __uint_as_float(bw[i] << 16);
            float v1 = __uint_as_float(bw[i] & 0xFFFF0000u);
            float h0 = fmaxf(u0 + v0, 0.f);
            float h1 = fmaxf(u1 + v1, 0.f);
            acc = fmaf(h0, W2[t * 8 + i * 2], acc);
            acc = fmaf(h1, W2[t * 8 + i * 2 + 1], acc);
        }
    }
    float x = acc + b2[0];
    out[e] = 1.f / (1.f + __expf(-x));
}

// ---------------------------------------------------------------------------
extern "C" void kernel_launch(void* const* d_in, const int* in_sizes, int n_in,
                              void* d_out, int out_size, void* d_ws, size_t ws_size,
                              hipStream_t stream) {
    const float* z  = (const float*)d_in[0];
    const int*   ei = (const int*)d_in[1];   // [2][N_EDGES]
    const float* W1 = (const float*)d_in[2]; // [256][64]
    const float* b1 = (const float*)d_in[3]; // [64]
    const float* W2 = (const float*)d_in[4]; // [64][1]
    const float* b2 = (const float*)d_in[5]; // [1]
    float* out = (float*)d_out;

    u16* WcatT = (u16*)d_ws;                           // 32 KB
    u16* UV    = (u16*)((char*)d_ws + 65536);          // 25.6 MB

    prep_kernel<<<64, 256, 0, stream>>>(W1, WcatT);
    gemm_kernel<<<(N_NODES + MT - 1) / MT, 256, 0, stream>>>(z, WcatT, b1, UV);
    edge_kernel<<<N_EDGES / 256, 256, 0, stream>>>(ei, UV, W2, b2, out);
}

// Round 2
// 173.400 us; speedup vs baseline: 1.1705x; 1.1705x over previous
//
#include <hip/hip_runtime.h>
#include <hip/hip_bf16.h>

#define N_NODES 100000
#define IN_DIM  128
#define HIDDEN  64
#define N_EDGES 1600000

typedef unsigned short u16;
typedef unsigned int   u32;

typedef __attribute__((ext_vector_type(8))) short bf16x8;  // 8 bf16 in 4 VGPRs
typedef __attribute__((ext_vector_type(4))) float f32x4;

__device__ __forceinline__ u16 f2bf(float f) {
    // round-to-nearest-even fp32 -> bf16
    u32 u = __float_as_uint(f);
    u32 r = 0x7FFFu + ((u >> 16) & 1u);
    u += r;
    return (u16)(u >> 16);
}

// ---------------------------------------------------------------------------
// Kernel 1: build WcatT[jj][k] (bf16, [128][128]) from W1 (fp32, [256][64]).
// Wcat[k][jj] = (jj < 64) ? W1[k][jj] : W1[128+k][jj-64]; stored transposed so
// MFMA B-fragment reads (n on lane&15, k contiguous) are 16B-contiguous.
// ---------------------------------------------------------------------------
__global__ __launch_bounds__(256) void prep_kernel(const float* __restrict__ W1,
                                                   u16* __restrict__ WcatT) {
    int idx = blockIdx.x * 256 + threadIdx.x;   // 0..16383
    int jj = idx >> 7;
    int k  = idx & 127;
    float v = (jj < 64) ? W1[k * 64 + jj] : W1[(128 + k) * 64 + (jj - 64)];
    WcatT[idx] = f2bf(v);
}

// ---------------------------------------------------------------------------
// Kernel 2: UV[m][jj] = sum_k z[m][k] * Wcat[k][jj]  (+ b1[jj] for jj<64)
// M-tile 64 per block (4 waves x 16 rows), N=128, K=128 single LDS tile.
// mfma_f32_16x16x32_bf16; A: m=lane&15, k=quad*8+j; B: n=lane&15, k=quad*8+j;
// D: col=lane&15, row=quad*4+reg (m89/m91-verified mappings).
// ---------------------------------------------------------------------------
#define MT  64
#define LDK 136   // 128 + 8 bf16 pad -> row stride 272 B (16B-aligned, breaks conflicts)

__global__ __launch_bounds__(256) void gemm_kernel(const float* __restrict__ z,
                                                   const u16* __restrict__ WcatT,
                                                   const float* __restrict__ b1,
                                                   u16* __restrict__ UV) {
    __shared__ u16 As[MT * LDK];    // 64 x 136 bf16  (17.4 KB)
    __shared__ u16 Bs[128 * LDK];   // 128 x 136 bf16 (34.8 KB)

    int tid = threadIdx.x;
    int m0  = blockIdx.x * MT;

    // Stage B (already bf16 in ws): 128 rows x 16 chunks of 16 B
    for (int c = tid; c < 128 * 16; c += 256) {
        int row = c >> 4, cc = c & 15;
        uint4 v = *(const uint4*)(WcatT + row * 128 + cc * 8);
        *(uint4*)(Bs + row * LDK + cc * 8) = v;
    }
    // Stage A with fp32->bf16 convert: 64 rows x 32 chunks of 4 floats
    for (int c = tid; c < MT * 32; c += 256) {
        int row = c >> 5, cc = c & 31;
        int gm = m0 + row;
        if (gm >= N_NODES) gm = N_NODES - 1;   // clamp; stores are guarded below
        float4 f = *(const float4*)(z + (size_t)gm * 128 + cc * 4);
        u32 lo = (u32)f2bf(f.x) | ((u32)f2bf(f.y) << 16);
        u32 hi = (u32)f2bf(f.z) | ((u32)f2bf(f.w) << 16);
        uint2 val; val.x = lo; val.y = hi;
        *(uint2*)(As + row * LDK + cc * 4) = val;
    }
    __syncthreads();

    int wave = tid >> 6;
    int lane = tid & 63;
    int quad = lane >> 4;
    int l16  = lane & 15;

    f32x4 acc[8];
    const f32x4 z4 = {0.f, 0.f, 0.f, 0.f};
#pragma unroll
    for (int i = 0; i < 8; i++) acc[i] = z4;

    int arow = wave * 16 + l16;   // local m for the A fragment
#pragma unroll
    for (int kb = 0; kb < 4; kb++) {
        int k0 = kb * 32 + quad * 8;
        bf16x8 a = *(const bf16x8*)(As + arow * LDK + k0);
#pragma unroll
        for (int nt = 0; nt < 8; nt++) {
            bf16x8 b = *(const bf16x8*)(Bs + (nt * 16 + l16) * LDK + k0);
            acc[nt] = __builtin_amdgcn_mfma_f32_16x16x32_bf16(a, b, acc[nt], 0, 0, 0);
        }
    }

    // Epilogue: add b1 to cols 0..63 (the U half), store bf16
#pragma unroll
    for (int nt = 0; nt < 8; nt++) {
        int col = nt * 16 + l16;
        float bias = (col < HIDDEN) ? b1[col] : 0.f;
#pragma unroll
        for (int r = 0; r < 4; r++) {
            int row = m0 + wave * 16 + quad * 4 + r;
            if (row < N_NODES) {
                UV[(size_t)row * 128 + col] = f2bf(acc[nt][r] + bias);
            }
        }
    }
}

// ---------------------------------------------------------------------------
// Kernel 3: lane-cooperative edge MLP.
// 8 lanes per edge: lane c loads 16-B chunk c of U[src] and of V[dst], does a
// partial relu-dot with its W2 slice, then 3-step butterfly reduce within the
// 8-lane group. 4 cache-line transactions per edge (the bf16 minimum) vs 16
// lookups in the one-thread-per-edge version.
// ---------------------------------------------------------------------------
#define EDGE_ITERS 8   // edges per wave = 8 subs * 8 iters = 64

__global__ __launch_bounds__(256) void edge_kernel(const int* __restrict__ ei,
                                                   const u16* __restrict__ UV,
                                                   const float* __restrict__ W2,
                                                   const float* __restrict__ b2,
                                                   float* __restrict__ out) {
    int gwave = (blockIdx.x * 256 + threadIdx.x) >> 6;  // global wave id
    int lane  = threadIdx.x & 63;
    int sub   = lane >> 3;   // 0..7: edge slot within wave
    int c     = lane & 7;    // 16-B chunk id within the 64-col half

    // Per-lane W2 slice (cols c*8 .. c*8+7), loaded once.
    float4 w2a = *(const float4*)(W2 + c * 8);
    float4 w2b = *(const float4*)(W2 + c * 8 + 4);
    float w2r[8] = {w2a.x, w2a.y, w2a.z, w2a.w, w2b.x, w2b.y, w2b.z, w2b.w};
    float b2v = b2[0];

    int ebase = gwave * (8 * EDGE_ITERS) + sub;

#pragma unroll
    for (int it = 0; it < EDGE_ITERS; ++it) {
        int e = ebase + it * 8;
        int s = ei[e];
        int d = ei[N_EDGES + e];
        uint4 a = *(const uint4*)(UV + (size_t)s * 128 + c * 8);        // U chunk
        uint4 b = *(const uint4*)(UV + (size_t)d * 128 + 64 + c * 8);   // V chunk
        u32 aw[4] = {a.x, a.y, a.z, a.w};
        u32 bw[4] = {b.x, b.y, b.z, b.w};
        float acc = 0.f;
#pragma unroll
        for (int i = 0; i < 4; i++) {
            float u0 = __uint_as_float(aw[i] << 16);
            float u1 = __uint_as_float(aw[i] & 0xFFFF0000u);
            float v0 = __uint_as_float(bw[i] << 16);
            float v1 = __uint_as_float(bw[i] & 0xFFFF0000u);
            float h0 = fmaxf(u0 + v0, 0.f);
            float h1 = fmaxf(u1 + v1, 0.f);
            acc = fmaf(h0, w2r[i * 2], acc);
            acc = fmaf(h1, w2r[i * 2 + 1], acc);
        }
        // Butterfly reduce across the 8-lane group (xor 1,2,4 stay in-group).
        acc += __shfl_xor(acc, 1);
        acc += __shfl_xor(acc, 2);
        acc += __shfl_xor(acc, 4);
        if (c == 0) {
            float x = acc + b2v;
            out[e] = 1.f / (1.f + __expf(-x));
        }
    }
}

// ---------------------------------------------------------------------------
extern "C" void kernel_launch(void* const* d_in, const int* in_sizes, int n_in,
                              void* d_out, int out_size, void* d_ws, size_t ws_size,
                              hipStream_t stream) {
    const float* z  = (const float*)d_in[0];
    const int*   ei = (const int*)d_in[1];   // [2][N_EDGES]
    const float* W1 = (const float*)d_in[2]; // [256][64]
    const float* b1 = (const float*)d_in[3]; // [64]
    const float* W2 = (const float*)d_in[4]; // [64][1]
    const float* b2 = (const float*)d_in[5]; // [1]
    float* out = (float*)d_out;

    u16* WcatT = (u16*)d_ws;                           // 32 KB
    u16* UV    = (u16*)((char*)d_ws + 65536);          // 25.6 MB

    prep_kernel<<<64, 256, 0, stream>>>(W1, WcatT);
    gemm_kernel<<<(N_NODES + MT - 1) / MT, 256, 0, stream>>>(z, WcatT, b1, UV);
    // 1.6M edges / (64 edges per wave) = 25000 waves = 6250 blocks of 4 waves
    edge_kernel<<<6250, 256, 0, stream>>>(ei, UV, W2, b2, out);
}

// Round 3
// 170.288 us; speedup vs baseline: 1.1919x; 1.0183x over previous
//
#include <hip/hip_runtime.h>
#include <hip/hip_bf16.h>

#define N_NODES 100000
#define IN_DIM  128
#define HIDDEN  64
#define N_EDGES 1600000

typedef unsigned short u16;
typedef unsigned int   u32;

typedef __attribute__((ext_vector_type(8))) short bf16x8;  // 8 bf16 in 4 VGPRs
typedef __attribute__((ext_vector_type(4))) float f32x4;

__device__ __forceinline__ u16 f2bf(float f) {
    // round-to-nearest-even fp32 -> bf16
    u32 u = __float_as_uint(f);
    u32 r = 0x7FFFu + ((u >> 16) & 1u);
    u += r;
    return (u16)(u >> 16);
}

// ---------------------------------------------------------------------------
// Kernel 1: build WcatT[jj][k] (bf16, [128][128]) from W1 (fp32, [256][64]).
// ---------------------------------------------------------------------------
__global__ __launch_bounds__(256) void prep_kernel(const float* __restrict__ W1,
                                                   u16* __restrict__ WcatT) {
    int idx = blockIdx.x * 256 + threadIdx.x;   // 0..16383
    int jj = idx >> 7;
    int k  = idx & 127;
    float v = (jj < 64) ? W1[k * 64 + jj] : W1[(128 + k) * 64 + (jj - 64)];
    WcatT[idx] = f2bf(v);
}

// ---------------------------------------------------------------------------
// Kernel 2: UV[m][jj] = sum_k z[m][k] * Wcat[k][jj]  (+ b1[jj] for jj<64)
// (unchanged this round — held constant for attribution)
// ---------------------------------------------------------------------------
#define MT  64
#define LDK 136   // 128 + 8 bf16 pad -> row stride 272 B (16B-aligned, breaks conflicts)

__global__ __launch_bounds__(256) void gemm_kernel(const float* __restrict__ z,
                                                   const u16* __restrict__ WcatT,
                                                   const float* __restrict__ b1,
                                                   u16* __restrict__ UV) {
    __shared__ u16 As[MT * LDK];    // 64 x 136 bf16  (17.4 KB)
    __shared__ u16 Bs[128 * LDK];   // 128 x 136 bf16 (34.8 KB)

    int tid = threadIdx.x;
    int m0  = blockIdx.x * MT;

    for (int c = tid; c < 128 * 16; c += 256) {
        int row = c >> 4, cc = c & 15;
        uint4 v = *(const uint4*)(WcatT + row * 128 + cc * 8);
        *(uint4*)(Bs + row * LDK + cc * 8) = v;
    }
    for (int c = tid; c < MT * 32; c += 256) {
        int row = c >> 5, cc = c & 31;
        int gm = m0 + row;
        if (gm >= N_NODES) gm = N_NODES - 1;   // clamp; stores are guarded below
        float4 f = *(const float4*)(z + (size_t)gm * 128 + cc * 4);
        u32 lo = (u32)f2bf(f.x) | ((u32)f2bf(f.y) << 16);
        u32 hi = (u32)f2bf(f.z) | ((u32)f2bf(f.w) << 16);
        uint2 val; val.x = lo; val.y = hi;
        *(uint2*)(As + row * LDK + cc * 4) = val;
    }
    __syncthreads();

    int wave = tid >> 6;
    int lane = tid & 63;
    int quad = lane >> 4;
    int l16  = lane & 15;

    f32x4 acc[8];
    const f32x4 z4 = {0.f, 0.f, 0.f, 0.f};
#pragma unroll
    for (int i = 0; i < 8; i++) acc[i] = z4;

    int arow = wave * 16 + l16;
#pragma unroll
    for (int kb = 0; kb < 4; kb++) {
        int k0 = kb * 32 + quad * 8;
        bf16x8 a = *(const bf16x8*)(As + arow * LDK + k0);
#pragma unroll
        for (int nt = 0; nt < 8; nt++) {
            bf16x8 b = *(const bf16x8*)(Bs + (nt * 16 + l16) * LDK + k0);
            acc[nt] = __builtin_amdgcn_mfma_f32_16x16x32_bf16(a, b, acc[nt], 0, 0, 0);
        }
    }

#pragma unroll
    for (int nt = 0; nt < 8; nt++) {
        int col = nt * 16 + l16;
        float bias = (col < HIDDEN) ? b1[col] : 0.f;
#pragma unroll
        for (int r = 0; r < 4; r++) {
            int row = m0 + wave * 16 + quad * 4 + r;
            if (row < N_NODES) {
                UV[(size_t)row * 128 + col] = f2bf(acc[nt][r] + bias);
            }
        }
    }
}

// ---------------------------------------------------------------------------
// Kernel 3: lane-cooperative edge MLP with explicit ILP batching.
// 8 lanes per edge; edges processed in batches of 4 so that 8 UV gathers
// (4 U-rows + 4 V-rows) are in flight before any is consumed. Forces ~64 VGPR
// instead of the round-2 compiler choice of 20 (which serialized the misses).
// ---------------------------------------------------------------------------
#define EDGE_ITERS 8   // edges per wave = 8 subs * 8 iters = 64
#define BATCH 4

__global__ __launch_bounds__(256) void edge_kernel(const int* __restrict__ ei,
                                                   const u16* __restrict__ UV,
                                                   const float* __restrict__ W2,
                                                   const float* __restrict__ b2,
                                                   float* __restrict__ out) {
    int gwave = (blockIdx.x * 256 + threadIdx.x) >> 6;  // global wave id
    int lane  = threadIdx.x & 63;
    int sub   = lane >> 3;   // 0..7: edge slot within wave
    int c     = lane & 7;    // 16-B chunk id within the 64-col half

    // Per-lane W2 slice (cols c*8 .. c*8+7), loaded once.
    float4 w2a = *(const float4*)(W2 + c * 8);
    float4 w2b = *(const float4*)(W2 + c * 8 + 4);
    float w2r[8] = {w2a.x, w2a.y, w2a.z, w2a.w, w2b.x, w2b.y, w2b.z, w2b.w};
    float b2v = b2[0];

    int ebase = gwave * (8 * EDGE_ITERS) + sub;

#pragma unroll
    for (int it4 = 0; it4 < EDGE_ITERS; it4 += BATCH) {
        int sB[BATCH], dB[BATCH];
#pragma unroll
        for (int j = 0; j < BATCH; j++) {
            int e = ebase + (it4 + j) * 8;
            sB[j] = ei[e];
            dB[j] = ei[N_EDGES + e];
        }
        uint4 aB[BATCH], bB[BATCH];
#pragma unroll
        for (int j = 0; j < BATCH; j++) {
            aB[j] = *(const uint4*)(UV + (size_t)sB[j] * 128 + c * 8);        // U chunk
            bB[j] = *(const uint4*)(UV + (size_t)dB[j] * 128 + 64 + c * 8);   // V chunk
        }
#pragma unroll
        for (int j = 0; j < BATCH; j++) {
            u32 aw[4] = {aB[j].x, aB[j].y, aB[j].z, aB[j].w};
            u32 bw[4] = {bB[j].x, bB[j].y, bB[j].z, bB[j].w};
            float acc = 0.f;
#pragma unroll
            for (int i = 0; i < 4; i++) {
                float u0 = __uint_as_float(aw[i] << 16);
                float u1 = __uint_as_float(aw[i] & 0xFFFF0000u);
                float v0 = __uint_as_float(bw[i] << 16);
                float v1 = __uint_as_float(bw[i] & 0xFFFF0000u);
                float h0 = fmaxf(u0 + v0, 0.f);
                float h1 = fmaxf(u1 + v1, 0.f);
                acc = fmaf(h0, w2r[i * 2], acc);
                acc = fmaf(h1, w2r[i * 2 + 1], acc);
            }
            // Butterfly reduce across the 8-lane group (xor 1,2,4 stay in-group).
            acc += __shfl_xor(acc, 1);
            acc += __shfl_xor(acc, 2);
            acc += __shfl_xor(acc, 4);
            if (c == 0) {
                int e = ebase + (it4 + j) * 8;
                float x = acc + b2v;
                out[e] = 1.f / (1.f + __expf(-x));
            }
        }
    }
}

// ---------------------------------------------------------------------------
extern "C" void kernel_launch(void* const* d_in, const int* in_sizes, int n_in,
                              void* d_out, int out_size, void* d_ws, size_t ws_size,
                              hipStream_t stream) {
    const float* z  = (const float*)d_in[0];
    const int*   ei = (const int*)d_in[1];   // [2][N_EDGES]
    const float* W1 = (const float*)d_in[2]; // [256][64]
    const float* b1 = (const float*)d_in[3]; // [64]
    const float* W2 = (const float*)d_in[4]; // [64][1]
    const float* b2 = (const float*)d_in[5]; // [1]
    float* out = (float*)d_out;

    u16* WcatT = (u16*)d_ws;                           // 32 KB
    u16* UV    = (u16*)((char*)d_ws + 65536);          // 25.6 MB

    prep_kernel<<<64, 256, 0, stream>>>(W1, WcatT);
    gemm_kernel<<<(N_NODES + MT - 1) / MT, 256, 0, stream>>>(z, WcatT, b1, UV);
    // 1.6M edges / (64 edges per wave) = 25000 waves = 6250 blocks of 4 waves
    edge_kernel<<<6250, 256, 0, stream>>>(ei, UV, W2, b2, out);
}

// Round 4
// 164.227 us; speedup vs baseline: 1.2359x; 1.0369x over previous
//
#include <hip/hip_runtime.h>
#include <hip/hip_bf16.h>

#define N_NODES 100000
#define IN_DIM  128
#define HIDDEN  64
#define N_EDGES 1600000

typedef unsigned short u16;
typedef unsigned int   u32;

typedef __attribute__((ext_vector_type(8))) short bf16x8;  // 8 bf16 in 4 VGPRs
typedef __attribute__((ext_vector_type(4))) float f32x4;

__device__ __forceinline__ u16 f2bf(float f) {
    // round-to-nearest-even fp32 -> bf16
    u32 u = __float_as_uint(f);
    u32 r = 0x7FFFu + ((u >> 16) & 1u);
    u += r;
    return (u16)(u >> 16);
}

// ---------------------------------------------------------------------------
// Kernel 1: build WcatT[jj][k] (bf16, [128][128]) from W1 (fp32, [256][64]).
// ---------------------------------------------------------------------------
__global__ __launch_bounds__(256) void prep_kernel(const float* __restrict__ W1,
                                                   u16* __restrict__ WcatT) {
    int idx = blockIdx.x * 256 + threadIdx.x;   // 0..16383
    int jj = idx >> 7;
    int k  = idx & 127;
    float v = (jj < 64) ? W1[k * 64 + jj] : W1[(128 + k) * 64 + (jj - 64)];
    WcatT[idx] = f2bf(v);
}

// ---------------------------------------------------------------------------
// Kernel 2 (rewritten): persistent grid-stride GEMM.
//   UV[m][jj] = sum_k z[m][k]*Wcat[k][jj] (+ b1[jj] for jj<64)
// - B staged to LDS ONCE per block (one barrier total, was 1563 re-stagings)
// - A loaded global->register directly: MFMA A-layout (m=lane&15, k=quad*8+j)
//   = per-kb a dense 16-row x 128-B panel, fully coalesced, no LDS round-trip
// - 4 independent waves per block, each owns 16-row tiles via grid-stride;
//   no per-tile barriers. N_NODES/16 = 6250 tiles exactly (no tail guard).
// ---------------------------------------------------------------------------
#define LDK 136   // 128 + 8 bf16 pad -> row stride 272 B (16B-aligned)
#define GEMM_BLOCKS 625

__global__ __launch_bounds__(256) void gemm_kernel(const float* __restrict__ z,
                                                   const u16* __restrict__ WcatT,
                                                   const float* __restrict__ b1,
                                                   u16* __restrict__ UV) {
    __shared__ u16 Bs[128 * LDK];   // 128 x 136 bf16 (34.8 KB)

    int tid = threadIdx.x;
    // Stage B once: 128 rows x 16 chunks of 16 B
    for (int c = tid; c < 128 * 16; c += 256) {
        int row = c >> 4, cc = c & 15;
        *(uint4*)(Bs + row * LDK + cc * 8) = *(const uint4*)(WcatT + row * 128 + cc * 8);
    }
    __syncthreads();

    int wave = tid >> 6;
    int lane = tid & 63;
    int quad = lane >> 4;
    int l16  = lane & 15;

    int gwid   = blockIdx.x * 4 + wave;
    int nwaves = GEMM_BLOCKS * 4;
    const int NTILES = N_NODES / 16;   // 6250

    // Per-lane bias for the U half (cols nt*16+l16, nt<4 <=> col<64)
    float bias[4];
#pragma unroll
    for (int nt = 0; nt < 4; nt++) bias[nt] = b1[nt * 16 + l16];

    for (int t = gwid; t < NTILES; t += nwaves) {
        const float* zrow = z + (size_t)(t * 16 + l16) * 128;

        // A panel: 8 x float4 = this lane's 32 fp32 (k = kb*32+quad*8 .. +7)
        float4 fa[8];
#pragma unroll
        for (int kb = 0; kb < 4; kb++) {
            fa[kb * 2]     = *(const float4*)(zrow + kb * 32 + quad * 8);
            fa[kb * 2 + 1] = *(const float4*)(zrow + kb * 32 + quad * 8 + 4);
        }
        // Convert to bf16 A fragments
        bf16x8 afrag[4];
#pragma unroll
        for (int kb = 0; kb < 4; kb++) {
            union { bf16x8 v; u32 w[4]; } pk;
            float4 lo = fa[kb * 2], hi = fa[kb * 2 + 1];
            pk.w[0] = (u32)f2bf(lo.x) | ((u32)f2bf(lo.y) << 16);
            pk.w[1] = (u32)f2bf(lo.z) | ((u32)f2bf(lo.w) << 16);
            pk.w[2] = (u32)f2bf(hi.x) | ((u32)f2bf(hi.y) << 16);
            pk.w[3] = (u32)f2bf(hi.z) | ((u32)f2bf(hi.w) << 16);
            afrag[kb] = pk.v;
        }

        f32x4 acc[8];
        const f32x4 z4 = {0.f, 0.f, 0.f, 0.f};
#pragma unroll
        for (int i = 0; i < 8; i++) acc[i] = z4;

#pragma unroll
        for (int kb = 0; kb < 4; kb++) {
            int k0 = kb * 32 + quad * 8;
#pragma unroll
            for (int nt = 0; nt < 8; nt++) {
                bf16x8 b = *(const bf16x8*)(Bs + (nt * 16 + l16) * LDK + k0);
                acc[nt] = __builtin_amdgcn_mfma_f32_16x16x32_bf16(afrag[kb], b, acc[nt], 0, 0, 0);
            }
        }

        // Epilogue: D layout col=lane&15, row=quad*4+reg
#pragma unroll
        for (int nt = 0; nt < 8; nt++) {
            float bb = (nt < 4) ? bias[nt] : 0.f;
#pragma unroll
            for (int r = 0; r < 4; r++) {
                int row = t * 16 + quad * 4 + r;
                UV[(size_t)row * 128 + nt * 16 + l16] = f2bf(acc[nt][r] + bb);
            }
        }
    }
}

// ---------------------------------------------------------------------------
// Kernel 3: lane-cooperative edge MLP (unchanged from round 3 for attribution)
// ---------------------------------------------------------------------------
#define EDGE_ITERS 8   // edges per wave = 8 subs * 8 iters = 64
#define BATCH 4

__global__ __launch_bounds__(256) void edge_kernel(const int* __restrict__ ei,
                                                   const u16* __restrict__ UV,
                                                   const float* __restrict__ W2,
                                                   const float* __restrict__ b2,
                                                   float* __restrict__ out) {
    int gwave = (blockIdx.x * 256 + threadIdx.x) >> 6;  // global wave id
    int lane  = threadIdx.x & 63;
    int sub   = lane >> 3;   // 0..7: edge slot within wave
    int c     = lane & 7;    // 16-B chunk id within the 64-col half

    float4 w2a = *(const float4*)(W2 + c * 8);
    float4 w2b = *(const float4*)(W2 + c * 8 + 4);
    float w2r[8] = {w2a.x, w2a.y, w2a.z, w2a.w, w2b.x, w2b.y, w2b.z, w2b.w};
    float b2v = b2[0];

    int ebase = gwave * (8 * EDGE_ITERS) + sub;

#pragma unroll
    for (int it4 = 0; it4 < EDGE_ITERS; it4 += BATCH) {
        int sB[BATCH], dB[BATCH];
#pragma unroll
        for (int j = 0; j < BATCH; j++) {
            int e = ebase + (it4 + j) * 8;
            sB[j] = ei[e];
            dB[j] = ei[N_EDGES + e];
        }
        uint4 aB[BATCH], bB[BATCH];
#pragma unroll
        for (int j = 0; j < BATCH; j++) {
            aB[j] = *(const uint4*)(UV + (size_t)sB[j] * 128 + c * 8);        // U chunk
            bB[j] = *(const uint4*)(UV + (size_t)dB[j] * 128 + 64 + c * 8);   // V chunk
        }
#pragma unroll
        for (int j = 0; j < BATCH; j++) {
            u32 aw[4] = {aB[j].x, aB[j].y, aB[j].z, aB[j].w};
            u32 bw[4] = {bB[j].x, bB[j].y, bB[j].z, bB[j].w};
            float acc = 0.f;
#pragma unroll
            for (int i = 0; i < 4; i++) {
                float u0 = __uint_as_float(aw[i] << 16);
                float u1 = __uint_as_float(aw[i] & 0xFFFF0000u);
                float v0 = __uint_as_float(bw[i] << 16);
                float v1 = __uint_as_float(bw[i] & 0xFFFF0000u);
                float h0 = fmaxf(u0 + v0, 0.f);
                float h1 = fmaxf(u1 + v1, 0.f);
                acc = fmaf(h0, w2r[i * 2], acc);
                acc = fmaf(h1, w2r[i * 2 + 1], acc);
            }
            acc += __shfl_xor(acc, 1);
            acc += __shfl_xor(acc, 2);
            acc += __shfl_xor(acc, 4);
            if (c == 0) {
                int e = ebase + (it4 + j) * 8;
                float x = acc + b2v;
                out[e] = 1.f / (1.f + __expf(-x));
            }
        }
    }
}

// ---------------------------------------------------------------------------
extern "C" void kernel_launch(void* const* d_in, const int* in_sizes, int n_in,
                              void* d_out, int out_size, void* d_ws, size_t ws_size,
                              hipStream_t stream) {
    const float* z  = (const float*)d_in[0];
    const int*   ei = (const int*)d_in[1];   // [2][N_EDGES]
    const float* W1 = (const float*)d_in[2]; // [256][64]
    const float* b1 = (const float*)d_in[3]; // [64]
    const float* W2 = (const float*)d_in[4]; // [64][1]
    const float* b2 = (const float*)d_in[5]; // [1]
    float* out = (float*)d_out;

    u16* WcatT = (u16*)d_ws;                           // 32 KB
    u16* UV    = (u16*)((char*)d_ws + 65536);          // 25.6 MB

    prep_kernel<<<64, 256, 0, stream>>>(W1, WcatT);
    gemm_kernel<<<GEMM_BLOCKS, 256, 0, stream>>>(z, WcatT, b1, UV);
    // 1.6M edges / (64 edges per wave) = 25000 waves = 6250 blocks of 4 waves
    edge_kernel<<<6250, 256, 0, stream>>>(ei, UV, W2, b2, out);
}

// Round 6
// 151.646 us; speedup vs baseline: 1.3384x; 1.0830x over previous
//
#include <hip/hip_runtime.h>
#include <hip/hip_bf16.h>

#define N_NODES 100000
#define IN_DIM  128
#define HIDDEN  64
#define N_EDGES 1600000

typedef unsigned short u16;
typedef unsigned int   u32;
typedef unsigned char  u8;

typedef __attribute__((ext_vector_type(8))) short bf16x8;  // 8 bf16 in 4 VGPRs
typedef __attribute__((ext_vector_type(4))) float f32x4;
typedef __attribute__((ext_vector_type(2))) float f32x2;

__device__ __forceinline__ u16 f2bf(float f) {
    // round-to-nearest-even fp32 -> bf16
    u32 u = __float_as_uint(f);
    u32 r = 0x7FFFu + ((u >> 16) & 1u);
    u += r;
    return (u16)(u >> 16);
}

__device__ __forceinline__ u8 f2fp8(float f) {
    // fp32 -> OCP e4m3 via HW cvt (RNE, satfinite)
    u32 p = (u32)__builtin_amdgcn_cvt_pk_fp8_f32(f, f, 0, false);
    return (u8)(p & 0xFF);
}

// ---------------------------------------------------------------------------
// Kernel 1: build WcatT[jj][k] (bf16, [128][128]) from W1 (fp32, [256][64]).
// ---------------------------------------------------------------------------
__global__ __launch_bounds__(256) void prep_kernel(const float* __restrict__ W1,
                                                   u16* __restrict__ WcatT) {
    int idx = blockIdx.x * 256 + threadIdx.x;   // 0..16383
    int jj = idx >> 7;
    int k  = idx & 127;
    float v = (jj < 64) ? W1[k * 64 + jj] : W1[(128 + k) * 64 + (jj - 64)];
    WcatT[idx] = f2bf(v);
}

// ---------------------------------------------------------------------------
// Kernel 2: persistent grid-stride GEMM (bf16 MFMA), epilogue quantizes the
// pre-activations to fp8 e4m3: UVq[node][128] bytes, U=cols 0..63 (1 cache
// line), V=cols 64..127 (1 line). Halves edge-phase line traffic.
// ---------------------------------------------------------------------------
#define LDK 136   // 128 + 8 bf16 pad -> row stride 272 B (16B-aligned)
#define GEMM_BLOCKS 625

__global__ __launch_bounds__(256) void gemm_kernel(const float* __restrict__ z,
                                                   const u16* __restrict__ WcatT,
                                                   const float* __restrict__ b1,
                                                   u8* __restrict__ UVq) {
    __shared__ u16 Bs[128 * LDK];   // 128 x 136 bf16 (34.8 KB)

    int tid = threadIdx.x;
    for (int c = tid; c < 128 * 16; c += 256) {
        int row = c >> 4, cc = c & 15;
        *(uint4*)(Bs + row * LDK + cc * 8) = *(const uint4*)(WcatT + row * 128 + cc * 8);
    }
    __syncthreads();

    int wave = tid >> 6;
    int lane = tid & 63;
    int quad = lane >> 4;
    int l16  = lane & 15;

    int gwid   = blockIdx.x * 4 + wave;
    int nwaves = GEMM_BLOCKS * 4;
    const int NTILES = N_NODES / 16;   // 6250

    float bias[4];
#pragma unroll
    for (int nt = 0; nt < 4; nt++) bias[nt] = b1[nt * 16 + l16];

    for (int t = gwid; t < NTILES; t += nwaves) {
        const float* zrow = z + (size_t)(t * 16 + l16) * 128;

        float4 fa[8];
#pragma unroll
        for (int kb = 0; kb < 4; kb++) {
            fa[kb * 2]     = *(const float4*)(zrow + kb * 32 + quad * 8);
            fa[kb * 2 + 1] = *(const float4*)(zrow + kb * 32 + quad * 8 + 4);
        }
        bf16x8 afrag[4];
#pragma unroll
        for (int kb = 0; kb < 4; kb++) {
            union { bf16x8 v; u32 w[4]; } pk;
            float4 lo = fa[kb * 2], hi = fa[kb * 2 + 1];
            pk.w[0] = (u32)f2bf(lo.x) | ((u32)f2bf(lo.y) << 16);
            pk.w[1] = (u32)f2bf(lo.z) | ((u32)f2bf(lo.w) << 16);
            pk.w[2] = (u32)f2bf(hi.x) | ((u32)f2bf(hi.y) << 16);
            pk.w[3] = (u32)f2bf(hi.z) | ((u32)f2bf(hi.w) << 16);
            afrag[kb] = pk.v;
        }

        f32x4 acc[8];
        const f32x4 z4 = {0.f, 0.f, 0.f, 0.f};
#pragma unroll
        for (int i = 0; i < 8; i++) acc[i] = z4;

#pragma unroll
        for (int kb = 0; kb < 4; kb++) {
            int k0 = kb * 32 + quad * 8;
#pragma unroll
            for (int nt = 0; nt < 8; nt++) {
                bf16x8 b = *(const bf16x8*)(Bs + (nt * 16 + l16) * LDK + k0);
                acc[nt] = __builtin_amdgcn_mfma_f32_16x16x32_bf16(afrag[kb], b, acc[nt], 0, 0, 0);
            }
        }

        // Epilogue: D layout col=lane&15, row=quad*4+reg; quantize to e4m3
#pragma unroll
        for (int nt = 0; nt < 8; nt++) {
            float bb = (nt < 4) ? bias[nt] : 0.f;
#pragma unroll
            for (int r = 0; r < 4; r++) {
                int row = t * 16 + quad * 4 + r;
                UVq[(size_t)row * 128 + nt * 16 + l16] = f2fp8(acc[nt][r] + bb);
            }
        }
    }
}

// ---------------------------------------------------------------------------
// Kernel 3: lane-cooperative edge MLP over the fp8 UV table.
// 8 lanes per edge, each lane owns 8 consecutive hidden cols (8 B of U, 8 B of
// V). Per 8-lane group: U row = 1 cache line, V row = 1 line (bf16 needed 2+2).
// BATCH=8 edges: all 16 idx loads + 16 gathers issued before a scheduling
// fence, forcing many outstanding vmem per thread (round 2/3 got ~2).
// ---------------------------------------------------------------------------
#define BATCH 8   // edges per wave = 8 subs * 8 batch = 64

__global__ __launch_bounds__(256, 2) void edge_kernel(const int* __restrict__ ei,
                                                      const u8* __restrict__ UVq,
                                                      const float* __restrict__ W2,
                                                      const float* __restrict__ b2,
                                                      float* __restrict__ out) {
    int gwave = (blockIdx.x * 256 + threadIdx.x) >> 6;  // global wave id
    int lane  = threadIdx.x & 63;
    int sub   = lane >> 3;   // 0..7: edge slot within wave
    int c     = lane & 7;    // 8-B chunk id (8 fp8 cols) within the 64-col half

    // Per-lane W2 slice (cols c*8 .. c*8+7), loaded once.
    float4 w2a = *(const float4*)(W2 + c * 8);
    float4 w2b = *(const float4*)(W2 + c * 8 + 4);
    float w2r[8] = {w2a.x, w2a.y, w2a.z, w2a.w, w2b.x, w2b.y, w2b.z, w2b.w};
    float b2v = b2[0];

    int ebase = gwave * 64 + sub;

    // --- load cluster: 16 idx loads + 16 gathers, all before the fence ---
    int sB[BATCH], dB[BATCH];
#pragma unroll
    for (int j = 0; j < BATCH; j++) {
        int e = ebase + j * 8;
        sB[j] = __builtin_nontemporal_load(ei + e);
        dB[j] = __builtin_nontemporal_load(ei + N_EDGES + e);
    }
    uint2 aB[BATCH], bB[BATCH];
#pragma unroll
    for (int j = 0; j < BATCH; j++) {
        aB[j] = *(const uint2*)(UVq + (size_t)sB[j] * 128 + c * 8);        // U chunk
        bB[j] = *(const uint2*)(UVq + (size_t)dB[j] * 128 + 64 + c * 8);   // V chunk
    }
    __builtin_amdgcn_sched_barrier(0);

    // --- compute ---
#pragma unroll
    for (int j = 0; j < BATCH; j++) {
        u32 aw[2] = {aB[j].x, aB[j].y};
        u32 bw[2] = {bB[j].x, bB[j].y};
        float acc = 0.f;
#pragma unroll
        for (int i = 0; i < 2; i++) {
            // word-select must be an immediate: manual unroll (false=lo, true=hi)
            f32x2 uu0 = __builtin_amdgcn_cvt_pk_f32_fp8(aw[i], false);
            f32x2 vv0 = __builtin_amdgcn_cvt_pk_f32_fp8(bw[i], false);
            f32x2 uu1 = __builtin_amdgcn_cvt_pk_f32_fp8(aw[i], true);
            f32x2 vv1 = __builtin_amdgcn_cvt_pk_f32_fp8(bw[i], true);
            float h0 = fmaxf(uu0.x + vv0.x, 0.f);
            float h1 = fmaxf(uu0.y + vv0.y, 0.f);
            float h2 = fmaxf(uu1.x + vv1.x, 0.f);
            float h3 = fmaxf(uu1.y + vv1.y, 0.f);
            acc = fmaf(h0, w2r[i * 4 + 0], acc);
            acc = fmaf(h1, w2r[i * 4 + 1], acc);
            acc = fmaf(h2, w2r[i * 4 + 2], acc);
            acc = fmaf(h3, w2r[i * 4 + 3], acc);
        }
        // Butterfly reduce across the 8-lane group (xor 1,2,4 stay in-group).
        acc += __shfl_xor(acc, 1);
        acc += __shfl_xor(acc, 2);
        acc += __shfl_xor(acc, 4);
        if (c == 0) {
            float x = acc + b2v;
            __builtin_nontemporal_store(1.f / (1.f + __expf(-x)), out + ebase + j * 8);
        }
    }
}

// ---------------------------------------------------------------------------
extern "C" void kernel_launch(void* const* d_in, const int* in_sizes, int n_in,
                              void* d_out, int out_size, void* d_ws, size_t ws_size,
                              hipStream_t stream) {
    const float* z  = (const float*)d_in[0];
    const int*   ei = (const int*)d_in[1];   // [2][N_EDGES]
    const float* W1 = (const float*)d_in[2]; // [256][64]
    const float* b1 = (const float*)d_in[3]; // [64]
    const float* W2 = (const float*)d_in[4]; // [64][1]
    const float* b2 = (const float*)d_in[5]; // [1]
    float* out = (float*)d_out;

    u16* WcatT = (u16*)d_ws;                           // 32 KB
    u8*  UVq   = (u8*)((char*)d_ws + 65536);           // 12.8 MB fp8 table

    prep_kernel<<<64, 256, 0, stream>>>(W1, WcatT);
    gemm_kernel<<<GEMM_BLOCKS, 256, 0, stream>>>(z, WcatT, b1, UVq);
    // 1.6M edges / (64 edges per wave) = 25000 waves = 6250 blocks of 4 waves
    edge_kernel<<<6250, 256, 0, stream>>>(ei, UVq, W2, b2, out);
}